// Round 1
// 817.077 us; speedup vs baseline: 1.2926x; 1.2926x over previous
//
#include <hip/hip_runtime.h>

// ---------------------------------------------------------------------------
// CenterPointHead on MI355X — bf16 MFMA implicit-GEMM, LDS-staged taps (R4).
//
// conv3x3 as 9-tap shifted GEMM. Per 32-channel K-slice, the block's input
// halo tile (6 rows x 66 cols x 32ch bf16 = 25.6 KB) is staged into LDS via
// global_load_lds (width 16, linear lane->LDS dest, OOB lanes read a zeroed
// page), double-buffered with a 2-barrier prefetch loop. All 9 taps then
// read B-frags from LDS (ds_read_b128, 64B pixel stride = conflict-free
// floor), giving 9x reuse vs the previous direct-global version.
// mfma_f32_16x16x32_bf16: A[m=lane&15][k=quad*8+j], B[k=quad*8+j][n=lane&15],
// D[m=quad*4+reg][n=lane&15]  (m89/m91-verified C/D layout).
// Wave tile: 64 oc x 64 px (4 M-tiles x 4 N-tiles, 64 acc regs).
// Block: 4 waves = 4 rows x 64 cols. Grid (5, 75, B). 3 blocks/CU (LDS).
// ---------------------------------------------------------------------------

typedef __attribute__((ext_vector_type(8))) short bf16x8;
typedef __attribute__((ext_vector_type(4))) float f32x4;

#define WIMG 300
#define HW 90000

__device__ __forceinline__ unsigned short f2bf(float f) {
    unsigned u = __float_as_uint(f);
    u += 0x7fff + ((u >> 16) & 1);   // round-to-nearest-even
    return (unsigned short)(u >> 16);
}

__device__ __forceinline__ void gload16(const unsigned short* g, unsigned short* l) {
    __builtin_amdgcn_global_load_lds(
        (const __attribute__((address_space(1))) void*)g,
        (__attribute__((address_space(3))) void*)l, 16, 0, 0);
}

// ---------------------------------------------------------------------------
// NCHW fp32 -> NHWC bf16 transpose, vectorized: float4 reads, b64 LDS ops,
// uint2 stores. LDS [ch][px] 32x132 (pad keeps b64 ops at the bank floor).
// ---------------------------------------------------------------------------
__global__ __launch_bounds__(256) void nchw2nhwc_bf16_k(
    const float* __restrict__ in_all,          // [B][256][90000]
    unsigned short* __restrict__ out_all)      // [B][90000][256]
{
    __shared__ unsigned short lds[32][132];
    const int p0 = blockIdx.x * 128;
    const int c0 = blockIdx.y * 32;
    const int b = blockIdx.z;
    const float* in = in_all + (size_t)b * 256 * HW;
    unsigned short* out = out_all + (size_t)b * HW * 256;
    const int t = threadIdx.x;

    // phase 1: each thread loads float4 (4 px of one channel), 4 rounds
#pragma unroll
    for (int i = 0; i < 4; ++i) {
        int task = i * 256 + t;            // 0..1023
        int c = task >> 5;                 // 0..31
        int p4 = (task & 31) * 4;          // 0..124
        const float* src = in + (size_t)(c0 + c) * HW + p0 + p4;
        float4 v;
        if (p0 + p4 + 3 < HW) {
            v = *(const float4*)src;
        } else {
            v.x = (p0 + p4 + 0 < HW) ? src[0] : 0.f;
            v.y = (p0 + p4 + 1 < HW) ? src[1] : 0.f;
            v.z = (p0 + p4 + 2 < HW) ? src[2] : 0.f;
            v.w = (p0 + p4 + 3 < HW) ? src[3] : 0.f;
        }
        uint2 pk;
        pk.x = (unsigned)f2bf(v.x) | ((unsigned)f2bf(v.y) << 16);
        pk.y = (unsigned)f2bf(v.z) | ((unsigned)f2bf(v.w) << 16);
        *(uint2*)&lds[c][p4] = pk;
    }
    __syncthreads();

    // phase 2: 4x4 micro-transpose in regs, uint2 (4ch) coalesced stores
    const int ct = t & 7;      // channel group of 4
    const int pt = t >> 3;     // pixel group of 4
    uint2 r[4];
#pragma unroll
    for (int j = 0; j < 4; ++j)
        r[j] = *(const uint2*)&lds[ct * 4 + j][pt * 4];
#pragma unroll
    for (int i = 0; i < 4; ++i) {
        unsigned e0 = (((i < 2) ? r[0].x : r[0].y) >> ((i & 1) * 16)) & 0xffffu;
        unsigned e1 = (((i < 2) ? r[1].x : r[1].y) >> ((i & 1) * 16)) & 0xffffu;
        unsigned e2 = (((i < 2) ? r[2].x : r[2].y) >> ((i & 1) * 16)) & 0xffffu;
        unsigned e3 = (((i < 2) ? r[3].x : r[3].y) >> ((i & 1) * 16)) & 0xffffu;
        uint2 o;
        o.x = e0 | (e1 << 16);
        o.y = e2 | (e3 << 16);
        int px = p0 + pt * 4 + i;
        if (px < HW)
            *(uint2*)&out[(size_t)px * 256 + c0 + ct * 4] = o;
    }
}

// ---------------------------------------------------------------------------
// Pack conv3x3 weights [64][CIN][3][3] fp32 -> A-frag bf16, layout
// [tap][ks][mt][lane][j]:  oc = mt*16+(lane&15), ic = ks*32+(lane>>4)*8+j.
// ---------------------------------------------------------------------------
__global__ __launch_bounds__(256) void pack_w_k(
    const float* __restrict__ w, unsigned short* __restrict__ apack, int CIN)
{
    const int KSUB = CIN / 32;
    const int tot = 9 * KSUB * 4 * 64 * 8;
    int idx = blockIdx.x * 256 + threadIdx.x;
    if (idx >= tot) return;
    int j = idx & 7;
    int lane = (idx >> 3) & 63;
    int rest = idx >> 9;
    int mt = rest & 3;
    int rest2 = rest >> 2;
    int ks = rest2 % KSUB;
    int tap = rest2 / KSUB;
    int oc = mt * 16 + (lane & 15);
    int ic = ks * 32 + (lane >> 4) * 8 + j;
    apack[idx] = f2bf(w[((size_t)oc * CIN + ic) * 9 + tap]);
}

// ---------------------------------------------------------------------------
// Fused conv3x3 + BN + ReLU (+ optional conv1x1 head) via MFMA, LDS-staged.
// NOUT == 0: trunk -> BN+ReLU -> NHWC bf16 store.
// NOUT  > 0: head  -> BN+ReLU -> 1x1(+bias) cross-quad shfl -> NCHW fp32.
// ---------------------------------------------------------------------------
template <int CIN, int NOUT>
__global__ __launch_bounds__(256, 3) void conv3_mfma_k(
    const unsigned short* __restrict__ in_all,   // [B][300][300][CIN] bf16
    const uint4* __restrict__ apack,             // [9][KSUB][4][64] x 16B
    const float* __restrict__ gg, const float* __restrict__ bb,
    const float* __restrict__ mm, const float* __restrict__ vv,
    const float* __restrict__ w2, const float* __restrict__ b2,
    unsigned short* __restrict__ out_nhwc_all,   // [B][300][300][64]
    float* __restrict__ out_f32_all,             // [B][NOUT][90000]
    const unsigned short* __restrict__ zp)       // 4 KB zero page
{
    constexpr int KSUB = CIN / 32;
    constexpr int TASKS = 396 * 4;               // 6 rows * 66 cols * 4 ch-groups
    __shared__ uint4 lds4[2][1600];              // 2 x 25.6 KB double buffer

    const int wave = threadIdx.x >> 6;
    const int lane = threadIdx.x & 63;
    const int n16 = lane & 15;
    const int quad = lane >> 4;
    const int x0 = blockIdx.x * 64;
    const int y0 = blockIdx.y * 4;
    const int y = y0 + wave;
    const int b = blockIdx.z;
    const unsigned short* inb = in_all + (size_t)b * HW * CIN;

    // Per-lane staging sources. Task t: ch-group s = t&3, px = t>>2,
    // tile row r = px/66 (image row y0-1+r), tile col c = px%66 (x0-1+c).
    // LDS dest byte = t*16 (linear in lane -> global_load_lds compatible).
    const unsigned short* sp[7];
#pragma unroll
    for (int i = 0; i < 7; ++i) {
        int task = i * 256 + wave * 64 + lane;
        int s = task & 3;
        int px = task >> 2;
        int r = px / 66;
        int c = px - r * 66;
        int ys = y0 - 1 + r;
        int xs = x0 - 1 + c;
        bool ok = (task < TASKS) && ((unsigned)ys < (unsigned)WIMG)
                                 && ((unsigned)xs < (unsigned)WIMG);
        sp[i] = ok ? (inb + ((size_t)ys * WIMG + xs) * CIN + s * 8) : zp;
    }

    f32x4 acc[4][4];
#pragma unroll
    for (int mt = 0; mt < 4; ++mt)
#pragma unroll
        for (int nt = 0; nt < 4; ++nt)
            acc[mt][nt] = (f32x4){0.f, 0.f, 0.f, 0.f};

    union U16 { uint4 u; bf16x8 h; };

    auto stage = [&](int buf, int ks) {
#pragma unroll
        for (int i = 0; i < 7; ++i) {
            int base = i * 256 + wave * 64;      // wave-uniform
            if (base < TASKS)                    // round 6: wave 0 only
                gload16(sp[i] + ks * 32, (unsigned short*)&lds4[buf][base]);
        }
    };

    // prologue: stage ks=0
    stage(0, 0);
    asm volatile("s_waitcnt vmcnt(0)" ::: "memory");
    __syncthreads();

    int cur = 0;
#pragma unroll 1
    for (int ks = 0; ks < KSUB; ++ks) {
        if (ks + 1 < KSUB)
            stage(cur ^ 1, ks + 1);              // async prefetch, drained at barrier
        const unsigned short* lp = (const unsigned short*)lds4[cur];
#pragma unroll
        for (int tap = 0; tap < 9; ++tap) {
            const int dy = tap / 3 - 1, dx = tap % 3 - 1;
            const int rbase = (wave + dy + 1) * 66 + dx + 1;
            U16 bf[4], a[4];
#pragma unroll
            for (int nt = 0; nt < 4; ++nt)
                bf[nt].u = *(const uint4*)(lp + (size_t)(rbase + nt * 16 + n16) * 32 + quad * 8);
#pragma unroll
            for (int mt = 0; mt < 4; ++mt)
                a[mt].u = apack[(size_t)(((tap * KSUB + ks) * 4 + mt) * 64) + lane];
#pragma unroll
            for (int mt = 0; mt < 4; ++mt)
#pragma unroll
                for (int nt = 0; nt < 4; ++nt)
                    acc[mt][nt] = __builtin_amdgcn_mfma_f32_16x16x32_bf16(
                        a[mt].h, bf[nt].h, acc[mt][nt], 0, 0, 0);
        }
        asm volatile("s_waitcnt vmcnt(0)" ::: "memory");
        __syncthreads();
        cur ^= 1;
    }

    // BN scale/shift for this lane's 16 channels (c = mt*16 + quad*4 + j)
    float scl[4][4], sft[4][4];
#pragma unroll
    for (int mt = 0; mt < 4; ++mt)
#pragma unroll
        for (int j = 0; j < 4; ++j) {
            int c = mt * 16 + quad * 4 + j;
            float s = gg[c] / sqrtf(vv[c] + 1e-5f);
            scl[mt][j] = s;
            sft[mt][j] = bb[c] - mm[c] * s;
        }

    if (NOUT == 0) {
        unsigned short* outb = out_nhwc_all + (size_t)b * HW * 64;
#pragma unroll
        for (int nt = 0; nt < 4; ++nt) {
            int xg = x0 + nt * 16 + n16;
            if (xg < WIMG) {
                unsigned short* op = outb + ((size_t)y * WIMG + xg) * 64 + quad * 4;
#pragma unroll
                for (int mt = 0; mt < 4; ++mt) {
                    union { unsigned short s[4]; uint2 u; } pk;
#pragma unroll
                    for (int j = 0; j < 4; ++j) {
                        float t = acc[mt][nt][j] * scl[mt][j] + sft[mt][j];
                        pk.s[j] = f2bf(t > 0.f ? t : 0.f);
                    }
                    *(uint2*)(op + mt * 16) = pk.u;
                }
            }
        }
    } else {
        // BN+ReLU in place
#pragma unroll
        for (int mt = 0; mt < 4; ++mt)
#pragma unroll
            for (int nt = 0; nt < 4; ++nt)
#pragma unroll
                for (int j = 0; j < 4; ++j) {
                    float t = acc[mt][nt][j] * scl[mt][j] + sft[mt][j];
                    acc[mt][nt][j] = t > 0.f ? t : 0.f;
                }
        float* outb = out_f32_all + (size_t)b * NOUT * HW;
#pragma unroll
        for (int no = 0; no < NOUT; ++no) {
            float wv[4][4];
#pragma unroll
            for (int mt = 0; mt < 4; ++mt)
#pragma unroll
                for (int j = 0; j < 4; ++j)
                    wv[mt][j] = w2[no * 64 + mt * 16 + quad * 4 + j];
#pragma unroll
            for (int nt = 0; nt < 4; ++nt) {
                float s = 0.f;
#pragma unroll
                for (int mt = 0; mt < 4; ++mt)
#pragma unroll
                    for (int j = 0; j < 4; ++j)
                        s += acc[mt][nt][j] * wv[mt][j];
                s += __shfl_xor(s, 16);
                s += __shfl_xor(s, 32);
                int xg = x0 + nt * 16 + n16;
                if (((no & 3) == quad) && xg < WIMG)
                    outb[(size_t)no * HW + (size_t)y * WIMG + xg] = s + b2[no];
            }
        }
    }
}

// ---------------------------------------------------------------------------
extern "C" void kernel_launch(void* const* d_in, const int* in_sizes, int n_in,
                              void* d_out, int out_size, void* d_ws, size_t ws_size,
                              hipStream_t stream) {
    const float* bev    = (const float*)d_in[0];
    const float* w_sh   = (const float*)d_in[1];
    const float* g_sh   = (const float*)d_in[2];
    const float* b_sh   = (const float*)d_in[3];
    const float* m_sh   = (const float*)d_in[4];
    const float* v_sh   = (const float*)d_in[5];
    const float* w_hm1  = (const float*)d_in[6];
    const float* g_hm1  = (const float*)d_in[7];
    const float* b_hm1  = (const float*)d_in[8];
    const float* m_hm1  = (const float*)d_in[9];
    const float* v_hm1  = (const float*)d_in[10];
    const float* w_hm2  = (const float*)d_in[11];
    const float* b_hm2  = (const float*)d_in[12];
    const float* w_reg1 = (const float*)d_in[13];
    const float* g_reg1 = (const float*)d_in[14];
    const float* b_reg1 = (const float*)d_in[15];
    const float* m_reg1 = (const float*)d_in[16];
    const float* v_reg1 = (const float*)d_in[17];
    const float* w_reg2 = (const float*)d_in[18];
    const float* b_reg2 = (const float*)d_in[19];

    // workspace layout (~231 MB; d_ws is ~1.44 GB)
    char* ws = (char*)d_ws;
    unsigned short* inbuf     = (unsigned short*)(ws);              // 184,320,000 B
    unsigned short* sharedbuf = (unsigned short*)(ws + 184320000);  //  46,080,000 B
    unsigned short* apk1      = (unsigned short*)(ws + 230400000);  //     294,912 B
    unsigned short* apkh      = (unsigned short*)(ws + 230694912);  //      73,728 B
    unsigned short* apkr      = (unsigned short*)(ws + 230768640);  //      73,728 B
    unsigned short* zp        = (unsigned short*)(ws + 230842368);  //       4,096 B

    float* heatmap = (float*)d_out;                       // [4][3][90000]
    float* box_reg = heatmap + (size_t)4 * 3 * HW;        // [4][8][90000]

    hipMemsetAsync(zp, 0, 4096, stream);   // zero page for OOB staging lanes

    pack_w_k<<<dim3(576), 256, 0, stream>>>(w_sh, apk1, 256);
    pack_w_k<<<dim3(144), 256, 0, stream>>>(w_hm1, apkh, 64);
    pack_w_k<<<dim3(144), 256, 0, stream>>>(w_reg1, apkr, 64);

    nchw2nhwc_bf16_k<<<dim3(704, 8, 4), 256, 0, stream>>>(bev, inbuf);

    const dim3 cgrid(5, 75, 4);   // 5*64 >= 300 cols, 75*4 = 300 rows, 4 batches
    conv3_mfma_k<256, 0><<<cgrid, 256, 0, stream>>>(
        inbuf, (const uint4*)apk1, g_sh, b_sh, m_sh, v_sh,
        nullptr, nullptr, sharedbuf, nullptr, zp);
    conv3_mfma_k<64, 3><<<cgrid, 256, 0, stream>>>(
        sharedbuf, (const uint4*)apkh, g_hm1, b_hm1, m_hm1, v_hm1,
        w_hm2, b_hm2, nullptr, heatmap, zp);
    conv3_mfma_k<64, 8><<<cgrid, 256, 0, stream>>>(
        sharedbuf, (const uint4*)apkr, g_reg1, b_reg1, m_reg1, v_reg1,
        w_reg2, b_reg2, nullptr, box_reg, zp);
}

// Round 2
// 816.085 us; speedup vs baseline: 1.2942x; 1.0012x over previous
//
#include <hip/hip_runtime.h>

// ---------------------------------------------------------------------------
// CenterPointHead on MI355X — bf16 MFMA implicit-GEMM, LDS-staged taps (R5).
//
// conv3x3 as 9-tap shifted GEMM. Per 32-channel K-slice, the block's input
// halo tile (6 rows x 66 cols x 32ch bf16 = 25.6 KB) is staged into LDS via
// global_load_lds (width 16, linear lane->LDS dest, OOB lanes read a zeroed
// page), double-buffered with a 2-barrier prefetch loop. All 9 taps then
// read B-frags from LDS (ds_read_b128, 64B pixel stride = conflict-free).
// R5: (a) both heads merged into one dual-head kernel (shared staging +
// shared B-frags, 2x MFMA per ds_read); (b) bijective chunked XCD swizzle
// (m204) on all conv grids for halo L2 reuse.
// mfma_f32_16x16x32_bf16: A[m=lane&15][k=quad*8+j], B[k=quad*8+j][n=lane&15],
// D[m=quad*4+reg][n=lane&15]  (m89/m91-verified C/D layout).
// Wave tile: 64 oc x 64 px (4 M-tiles x 4 N-tiles, 64 acc regs).
// Block: 4 waves = 4 rows x 64 cols. Grid 5*75*B = 1500 blocks.
// ---------------------------------------------------------------------------

typedef __attribute__((ext_vector_type(8))) short bf16x8;
typedef __attribute__((ext_vector_type(4))) float f32x4;

#define WIMG 300
#define HW 90000
#define NWG 1500   // 5 * 75 * 4 conv blocks, for the bijective XCD swizzle

__device__ __forceinline__ unsigned short f2bf(float f) {
    unsigned u = __float_as_uint(f);
    u += 0x7fff + ((u >> 16) & 1);   // round-to-nearest-even
    return (unsigned short)(u >> 16);
}

__device__ __forceinline__ void gload16(const unsigned short* g, unsigned short* l) {
    __builtin_amdgcn_global_load_lds(
        (const __attribute__((address_space(1))) void*)g,
        (__attribute__((address_space(3))) void*)l, 16, 0, 0);
}

// bijective chunked XCD swizzle (m204): each XCD gets ~NWG/8 consecutive tiles
__device__ __forceinline__ void swz_block(int& bx, int& by, int& bz) {
    const int orig = blockIdx.x + 5 * (blockIdx.y + 75 * blockIdx.z);
    const int q = NWG / 8, r = NWG % 8;          // 187, 4
    const int xcd = orig & 7, i = orig >> 3;
    const int wg = (xcd < r) ? xcd * (q + 1) + i
                             : r * (q + 1) + (xcd - r) * q + i;
    bx = wg % 5;
    const int rest = wg / 5;
    by = rest % 75;
    bz = rest / 75;
}

// ---------------------------------------------------------------------------
// NCHW fp32 -> NHWC bf16 transpose, vectorized: float4 reads, b64 LDS ops,
// uint2 stores. LDS [ch][px] 32x132 (pad keeps b64 ops at the bank floor).
// ---------------------------------------------------------------------------
__global__ __launch_bounds__(256) void nchw2nhwc_bf16_k(
    const float* __restrict__ in_all,          // [B][256][90000]
    unsigned short* __restrict__ out_all)      // [B][90000][256]
{
    __shared__ unsigned short lds[32][132];
    const int p0 = blockIdx.x * 128;
    const int c0 = blockIdx.y * 32;
    const int b = blockIdx.z;
    const float* in = in_all + (size_t)b * 256 * HW;
    unsigned short* out = out_all + (size_t)b * HW * 256;
    const int t = threadIdx.x;

    // phase 1: each thread loads float4 (4 px of one channel), 4 rounds
#pragma unroll
    for (int i = 0; i < 4; ++i) {
        int task = i * 256 + t;            // 0..1023
        int c = task >> 5;                 // 0..31
        int p4 = (task & 31) * 4;          // 0..124
        const float* src = in + (size_t)(c0 + c) * HW + p0 + p4;
        float4 v;
        if (p0 + p4 + 3 < HW) {
            v = *(const float4*)src;
        } else {
            v.x = (p0 + p4 + 0 < HW) ? src[0] : 0.f;
            v.y = (p0 + p4 + 1 < HW) ? src[1] : 0.f;
            v.z = (p0 + p4 + 2 < HW) ? src[2] : 0.f;
            v.w = (p0 + p4 + 3 < HW) ? src[3] : 0.f;
        }
        uint2 pk;
        pk.x = (unsigned)f2bf(v.x) | ((unsigned)f2bf(v.y) << 16);
        pk.y = (unsigned)f2bf(v.z) | ((unsigned)f2bf(v.w) << 16);
        *(uint2*)&lds[c][p4] = pk;
    }
    __syncthreads();

    // phase 2: 4x4 micro-transpose in regs, uint2 (4ch) coalesced stores
    const int ct = t & 7;      // channel group of 4
    const int pt = t >> 3;     // pixel group of 4
    uint2 r[4];
#pragma unroll
    for (int j = 0; j < 4; ++j)
        r[j] = *(const uint2*)&lds[ct * 4 + j][pt * 4];
#pragma unroll
    for (int i = 0; i < 4; ++i) {
        unsigned e0 = (((i < 2) ? r[0].x : r[0].y) >> ((i & 1) * 16)) & 0xffffu;
        unsigned e1 = (((i < 2) ? r[1].x : r[1].y) >> ((i & 1) * 16)) & 0xffffu;
        unsigned e2 = (((i < 2) ? r[2].x : r[2].y) >> ((i & 1) * 16)) & 0xffffu;
        unsigned e3 = (((i < 2) ? r[3].x : r[3].y) >> ((i & 1) * 16)) & 0xffffu;
        uint2 o;
        o.x = e0 | (e1 << 16);
        o.y = e2 | (e3 << 16);
        int px = p0 + pt * 4 + i;
        if (px < HW)
            *(uint2*)&out[(size_t)px * 256 + c0 + ct * 4] = o;
    }
}

// ---------------------------------------------------------------------------
// Pack conv3x3 weights [64][CIN][3][3] fp32 -> A-frag bf16, layout
// [tap][ks][mt][lane][j]:  oc = mt*16+(lane&15), ic = ks*32+(lane>>4)*8+j.
// ---------------------------------------------------------------------------
__global__ __launch_bounds__(256) void pack_w_k(
    const float* __restrict__ w, unsigned short* __restrict__ apack, int CIN)
{
    const int KSUB = CIN / 32;
    const int tot = 9 * KSUB * 4 * 64 * 8;
    int idx = blockIdx.x * 256 + threadIdx.x;
    if (idx >= tot) return;
    int j = idx & 7;
    int lane = (idx >> 3) & 63;
    int rest = idx >> 9;
    int mt = rest & 3;
    int rest2 = rest >> 2;
    int ks = rest2 % KSUB;
    int tap = rest2 / KSUB;
    int oc = mt * 16 + (lane & 15);
    int ic = ks * 32 + (lane >> 4) * 8 + j;
    apack[idx] = f2bf(w[((size_t)oc * CIN + ic) * 9 + tap]);
}

// ---------------------------------------------------------------------------
// Staging helpers shared by the conv kernels.
// Task t: ch-group s = t&3 (8 ch), px = t>>2; tile row r = px/66
// (image row y0-1+r), tile col c = px%66 (x0-1+c). LDS dest byte = t*16
// (linear in lane -> global_load_lds compatible).
// ---------------------------------------------------------------------------
#define TASKS (396 * 4)   // 6 rows * 66 cols * 4 ch-groups

template <int CIN>
__device__ __forceinline__ void make_sp(const unsigned short* inb,
                                        const unsigned short* zp,
                                        int x0, int y0, int wave, int lane,
                                        const unsigned short* (&sp)[7]) {
#pragma unroll
    for (int i = 0; i < 7; ++i) {
        int task = i * 256 + wave * 64 + lane;
        int s = task & 3;
        int px = task >> 2;
        int r = px / 66;
        int c = px - r * 66;
        int ys = y0 - 1 + r;
        int xs = x0 - 1 + c;
        bool ok = (task < TASKS) && ((unsigned)ys < (unsigned)WIMG)
                                 && ((unsigned)xs < (unsigned)WIMG);
        sp[i] = ok ? (inb + ((size_t)ys * WIMG + xs) * CIN + s * 8) : zp;
    }
}

__device__ __forceinline__ void stage_ks(const unsigned short* const (&sp)[7],
                                         uint4* dst, int wave, int ks) {
#pragma unroll
    for (int i = 0; i < 7; ++i) {
        int base = i * 256 + wave * 64;      // wave-uniform
        if (base < TASKS)                    // round 6: wave 0 only
            gload16(sp[i] + ks * 32, (unsigned short*)&dst[base]);
    }
}

// ---------------------------------------------------------------------------
// Trunk: fused conv3x3(256->64) + BN + ReLU via MFMA -> NHWC bf16 store.
// ---------------------------------------------------------------------------
__global__ __launch_bounds__(256, 3) void conv3_trunk_k(
    const unsigned short* __restrict__ in_all,   // [B][300][300][256] bf16
    const uint4* __restrict__ apack,             // [9][8][4][64] x 16B
    const float* __restrict__ gg, const float* __restrict__ bb,
    const float* __restrict__ mm, const float* __restrict__ vv,
    unsigned short* __restrict__ out_nhwc_all,   // [B][300][300][64]
    const unsigned short* __restrict__ zp)       // 4 KB zero page
{
    constexpr int CIN = 256, KSUB = 8;
    __shared__ uint4 lds4[2][1600];              // 2 x 25.6 KB double buffer

    const int wave = threadIdx.x >> 6;
    const int lane = threadIdx.x & 63;
    const int n16 = lane & 15;
    const int quad = lane >> 4;
    int bx, by, b;
    swz_block(bx, by, b);
    const int x0 = bx * 64;
    const int y0 = by * 4;
    const int y = y0 + wave;
    const unsigned short* inb = in_all + (size_t)b * HW * CIN;

    const unsigned short* sp[7];
    make_sp<CIN>(inb, zp, x0, y0, wave, lane, sp);

    f32x4 acc[4][4];
#pragma unroll
    for (int mt = 0; mt < 4; ++mt)
#pragma unroll
        for (int nt = 0; nt < 4; ++nt)
            acc[mt][nt] = (f32x4){0.f, 0.f, 0.f, 0.f};

    union U16 { uint4 u; bf16x8 h; };

    stage_ks(sp, lds4[0], wave, 0);
    asm volatile("s_waitcnt vmcnt(0)" ::: "memory");
    __syncthreads();

    int cur = 0;
#pragma unroll 1
    for (int ks = 0; ks < KSUB; ++ks) {
        if (ks + 1 < KSUB)
            stage_ks(sp, lds4[cur ^ 1], wave, ks + 1);   // async prefetch
        const unsigned short* lp = (const unsigned short*)lds4[cur];
#pragma unroll
        for (int tap = 0; tap < 9; ++tap) {
            const int dy = tap / 3 - 1, dx = tap % 3 - 1;
            const int rbase = (wave + dy + 1) * 66 + dx + 1;
            U16 bf[4], a[4];
#pragma unroll
            for (int nt = 0; nt < 4; ++nt)
                bf[nt].u = *(const uint4*)(lp + (size_t)(rbase + nt * 16 + n16) * 32 + quad * 8);
#pragma unroll
            for (int mt = 0; mt < 4; ++mt)
                a[mt].u = apack[(size_t)(((tap * KSUB + ks) * 4 + mt) * 64) + lane];
#pragma unroll
            for (int mt = 0; mt < 4; ++mt)
#pragma unroll
                for (int nt = 0; nt < 4; ++nt)
                    acc[mt][nt] = __builtin_amdgcn_mfma_f32_16x16x32_bf16(
                        a[mt].h, bf[nt].h, acc[mt][nt], 0, 0, 0);
        }
        asm volatile("s_waitcnt vmcnt(0)" ::: "memory");
        __syncthreads();
        cur ^= 1;
    }

    // BN scale/shift for this lane's 16 channels (c = mt*16 + quad*4 + j)
    float scl[4][4], sft[4][4];
#pragma unroll
    for (int mt = 0; mt < 4; ++mt)
#pragma unroll
        for (int j = 0; j < 4; ++j) {
            int c = mt * 16 + quad * 4 + j;
            float s = gg[c] / sqrtf(vv[c] + 1e-5f);
            scl[mt][j] = s;
            sft[mt][j] = bb[c] - mm[c] * s;
        }

    unsigned short* outb = out_nhwc_all + (size_t)b * HW * 64;
#pragma unroll
    for (int nt = 0; nt < 4; ++nt) {
        int xg = x0 + nt * 16 + n16;
        if (xg < WIMG) {
            unsigned short* op = outb + ((size_t)y * WIMG + xg) * 64 + quad * 4;
#pragma unroll
            for (int mt = 0; mt < 4; ++mt) {
                union { unsigned short s[4]; uint2 u; } pk;
#pragma unroll
                for (int j = 0; j < 4; ++j) {
                    float t = acc[mt][nt][j] * scl[mt][j] + sft[mt][j];
                    pk.s[j] = f2bf(t > 0.f ? t : 0.f);
                }
                *(uint2*)(op + mt * 16) = pk.u;
            }
        }
    }
}

// ---------------------------------------------------------------------------
// Dual head: one pass over the trunk output computes BOTH
//   hm:  conv3x3(64->64) + BN + ReLU -> 1x1(64->3)(+bias) -> NCHW fp32
//   reg: conv3x3(64->64) + BN + ReLU -> 1x1(64->8)(+bias) -> NCHW fp32
// sharing the LDS staging and every B-fragment ds_read (2x MFMA per read).
// ---------------------------------------------------------------------------
__global__ __launch_bounds__(256, 2) void conv3_dualhead_k(
    const unsigned short* __restrict__ in_all,   // [B][300][300][64] bf16
    const uint4* __restrict__ apack_h,           // [9][2][4][64] x 16B
    const uint4* __restrict__ apack_r,
    const float* __restrict__ g_h, const float* __restrict__ b_h,
    const float* __restrict__ m_h, const float* __restrict__ v_h,
    const float* __restrict__ g_r, const float* __restrict__ b_r,
    const float* __restrict__ m_r, const float* __restrict__ v_r,
    const float* __restrict__ w2_h, const float* __restrict__ b2_h,
    const float* __restrict__ w2_r, const float* __restrict__ b2_r,
    float* __restrict__ out_h_all,               // [B][3][90000]
    float* __restrict__ out_r_all,               // [B][8][90000]
    const unsigned short* __restrict__ zp)
{
    constexpr int CIN = 64, KSUB = 2;
    __shared__ uint4 lds4[2][1600];

    const int wave = threadIdx.x >> 6;
    const int lane = threadIdx.x & 63;
    const int n16 = lane & 15;
    const int quad = lane >> 4;
    int bx, by, b;
    swz_block(bx, by, b);
    const int x0 = bx * 64;
    const int y0 = by * 4;
    const int y = y0 + wave;
    const unsigned short* inb = in_all + (size_t)b * HW * CIN;

    const unsigned short* sp[7];
    make_sp<CIN>(inb, zp, x0, y0, wave, lane, sp);

    f32x4 acch[4][4], accr[4][4];
#pragma unroll
    for (int mt = 0; mt < 4; ++mt)
#pragma unroll
        for (int nt = 0; nt < 4; ++nt) {
            acch[mt][nt] = (f32x4){0.f, 0.f, 0.f, 0.f};
            accr[mt][nt] = (f32x4){0.f, 0.f, 0.f, 0.f};
        }

    union U16 { uint4 u; bf16x8 h; };

    stage_ks(sp, lds4[0], wave, 0);
    asm volatile("s_waitcnt vmcnt(0)" ::: "memory");
    __syncthreads();

    int cur = 0;
#pragma unroll 1
    for (int ks = 0; ks < KSUB; ++ks) {
        if (ks + 1 < KSUB)
            stage_ks(sp, lds4[cur ^ 1], wave, ks + 1);
        const unsigned short* lp = (const unsigned short*)lds4[cur];
#pragma unroll
        for (int tap = 0; tap < 9; ++tap) {
            const int dy = tap / 3 - 1, dx = tap % 3 - 1;
            const int rbase = (wave + dy + 1) * 66 + dx + 1;
            U16 bf[4];
#pragma unroll
            for (int nt = 0; nt < 4; ++nt)
                bf[nt].u = *(const uint4*)(lp + (size_t)(rbase + nt * 16 + n16) * 32 + quad * 8);
#pragma unroll
            for (int mt = 0; mt < 4; ++mt) {
                U16 ah, ar;
                size_t ai = (size_t)(((tap * KSUB + ks) * 4 + mt) * 64) + lane;
                ah.u = apack_h[ai];
                ar.u = apack_r[ai];
#pragma unroll
                for (int nt = 0; nt < 4; ++nt) {
                    acch[mt][nt] = __builtin_amdgcn_mfma_f32_16x16x32_bf16(
                        ah.h, bf[nt].h, acch[mt][nt], 0, 0, 0);
                    accr[mt][nt] = __builtin_amdgcn_mfma_f32_16x16x32_bf16(
                        ar.h, bf[nt].h, accr[mt][nt], 0, 0, 0);
                }
            }
        }
        asm volatile("s_waitcnt vmcnt(0)" ::: "memory");
        __syncthreads();
        cur ^= 1;
    }

    // Epilogue per head: BN+ReLU in place, then 1x1 + cross-quad shfl reduce.
    auto epi = [&](f32x4 (&acc)[4][4], const float* gg, const float* bb,
                   const float* mm, const float* vv, const float* w2,
                   const float* b2, int NOUT, float* outb) {
        float scl[4][4], sft[4][4];
#pragma unroll
        for (int mt = 0; mt < 4; ++mt)
#pragma unroll
            for (int j = 0; j < 4; ++j) {
                int c = mt * 16 + quad * 4 + j;
                float s = gg[c] / sqrtf(vv[c] + 1e-5f);
                scl[mt][j] = s;
                sft[mt][j] = bb[c] - mm[c] * s;
            }
#pragma unroll
        for (int mt = 0; mt < 4; ++mt)
#pragma unroll
            for (int nt = 0; nt < 4; ++nt)
#pragma unroll
                for (int j = 0; j < 4; ++j) {
                    float t = acc[mt][nt][j] * scl[mt][j] + sft[mt][j];
                    acc[mt][nt][j] = t > 0.f ? t : 0.f;
                }
        for (int no = 0; no < NOUT; ++no) {
            float wv[4][4];
#pragma unroll
            for (int mt = 0; mt < 4; ++mt)
#pragma unroll
                for (int j = 0; j < 4; ++j)
                    wv[mt][j] = w2[no * 64 + mt * 16 + quad * 4 + j];
#pragma unroll
            for (int nt = 0; nt < 4; ++nt) {
                float s = 0.f;
#pragma unroll
                for (int mt = 0; mt < 4; ++mt)
#pragma unroll
                    for (int j = 0; j < 4; ++j)
                        s += acc[mt][nt][j] * wv[mt][j];
                s += __shfl_xor(s, 16);
                s += __shfl_xor(s, 32);
                int xg = x0 + nt * 16 + n16;
                if (((no & 3) == quad) && xg < WIMG)
                    outb[(size_t)no * HW + (size_t)y * WIMG + xg] = s + b2[no];
            }
        }
    };

    epi(acch, g_h, b_h, m_h, v_h, w2_h, b2_h, 3, out_h_all + (size_t)b * 3 * HW);
    epi(accr, g_r, b_r, m_r, v_r, w2_r, b2_r, 8, out_r_all + (size_t)b * 8 * HW);
}

// ---------------------------------------------------------------------------
extern "C" void kernel_launch(void* const* d_in, const int* in_sizes, int n_in,
                              void* d_out, int out_size, void* d_ws, size_t ws_size,
                              hipStream_t stream) {
    const float* bev    = (const float*)d_in[0];
    const float* w_sh   = (const float*)d_in[1];
    const float* g_sh   = (const float*)d_in[2];
    const float* b_sh   = (const float*)d_in[3];
    const float* m_sh   = (const float*)d_in[4];
    const float* v_sh   = (const float*)d_in[5];
    const float* w_hm1  = (const float*)d_in[6];
    const float* g_hm1  = (const float*)d_in[7];
    const float* b_hm1  = (const float*)d_in[8];
    const float* m_hm1  = (const float*)d_in[9];
    const float* v_hm1  = (const float*)d_in[10];
    const float* w_hm2  = (const float*)d_in[11];
    const float* b_hm2  = (const float*)d_in[12];
    const float* w_reg1 = (const float*)d_in[13];
    const float* g_reg1 = (const float*)d_in[14];
    const float* b_reg1 = (const float*)d_in[15];
    const float* m_reg1 = (const float*)d_in[16];
    const float* v_reg1 = (const float*)d_in[17];
    const float* w_reg2 = (const float*)d_in[18];
    const float* b_reg2 = (const float*)d_in[19];

    // workspace layout (~231 MB; d_ws is ~1.44 GB)
    char* ws = (char*)d_ws;
    unsigned short* inbuf     = (unsigned short*)(ws);              // 184,320,000 B
    unsigned short* sharedbuf = (unsigned short*)(ws + 184320000);  //  46,080,000 B
    unsigned short* apk1      = (unsigned short*)(ws + 230400000);  //     294,912 B
    unsigned short* apkh      = (unsigned short*)(ws + 230694912);  //      73,728 B
    unsigned short* apkr      = (unsigned short*)(ws + 230768640);  //      73,728 B
    unsigned short* zp        = (unsigned short*)(ws + 230842368);  //       4,096 B

    float* heatmap = (float*)d_out;                       // [4][3][90000]
    float* box_reg = heatmap + (size_t)4 * 3 * HW;        // [4][8][90000]

    hipMemsetAsync(zp, 0, 4096, stream);   // zero page for OOB staging lanes

    pack_w_k<<<dim3(576), 256, 0, stream>>>(w_sh, apk1, 256);
    pack_w_k<<<dim3(144), 256, 0, stream>>>(w_hm1, apkh, 64);
    pack_w_k<<<dim3(144), 256, 0, stream>>>(w_reg1, apkr, 64);

    nchw2nhwc_bf16_k<<<dim3(704, 8, 4), 256, 0, stream>>>(bev, inbuf);

    const dim3 cgrid(5, 75, 4);   // 5*64 >= 300 cols, 75*4 = 300 rows, 4 batches
    conv3_trunk_k<<<cgrid, 256, 0, stream>>>(
        inbuf, (const uint4*)apk1, g_sh, b_sh, m_sh, v_sh, sharedbuf, zp);
    conv3_dualhead_k<<<cgrid, 256, 0, stream>>>(
        sharedbuf, (const uint4*)apkh, (const uint4*)apkr,
        g_hm1, b_hm1, m_hm1, v_hm1,
        g_reg1, b_reg1, m_reg1, v_reg1,
        w_hm2, b_hm2, w_reg2, b_reg2,
        heatmap, box_reg, zp);
}